// Round 1
// baseline (25658.026 us; speedup 1.0000x reference)
//
#include <hip/hip_runtime.h>

#define EMB    1024
#define HID    2048
#define VOCAB  50257
#define T      256
#define NB_LOG 1024        // blocks in logits kernel (also # argmax partials)
#define NB_GAT (HID / 4)   // 512 blocks, 4 waves each, 1 hidden unit per wave

#define NEG_INF (-3.402823466e38f)

// ---------------------------------------------------------------------------
// ws layout (floats):
//   [0,       HID)    hA   (h buffer, even steps read this)
//   [HID,    2HID)    hB
//   [2HID,   3HID)    c
//   [3HID,   3HID+NB_LOG)            block_max (f32)
//   [3HID+NB_LOG, 3HID+2*NB_LOG)     block_idx (i32, stored as raw)
// ---------------------------------------------------------------------------

__global__ void k_init(float* __restrict__ ws) {
    int i = blockIdx.x * blockDim.x + threadIdx.x;
    if (i < 3 * HID) ws[i] = 0.0f;   // hA, hB, c  <- zeros (ws is poisoned 0xAA)
}

// One wave per hidden unit j. Computes the 4 gate rows (i,f,g,o), updates c,h.
__global__ __launch_bounds__(256) void k_gates(
    const float* __restrict__ emb,
    const float* __restrict__ W_ih, const float* __restrict__ W_hh,
    const float* __restrict__ b_ih, const float* __restrict__ b_hh,
    const float* __restrict__ h_in, float* __restrict__ h_out,
    float* __restrict__ c,
    const float* __restrict__ bmax, const int* __restrict__ bidx,
    int step)
{
    __shared__ float xs[EMB];
    __shared__ float hs[HID];
    __shared__ float redv[4];
    __shared__ int   redi[4];
    __shared__ int   tok_s;

    const int tid  = threadIdx.x;
    const int wave = tid >> 6;
    const int lane = tid & 63;

    // ---- 1) determine tok (redundant per-block reduction of K2 partials) ----
    if (step == 0) {
        if (tid == 0) tok_s = 0;
    } else {
        float bv = NEG_INF; int bi = 0x7fffffff;
        for (int i = tid; i < NB_LOG; i += 256) {
            float v = bmax[i]; int ix = bidx[i];
            if (v > bv || (v == bv && ix < bi)) { bv = v; bi = ix; }
        }
        for (int off = 32; off; off >>= 1) {
            float ov = __shfl_down(bv, off);
            int   oi = __shfl_down(bi, off);
            if (ov > bv || (ov == bv && oi < bi)) { bv = ov; bi = oi; }
        }
        if (lane == 0) { redv[wave] = bv; redi[wave] = bi; }
        __syncthreads();
        if (tid == 0) {
            for (int w = 1; w < 4; ++w)
                if (redv[w] > bv || (redv[w] == bv && redi[w] < bi)) { bv = redv[w]; bi = redi[w]; }
            tok_s = bi;
        }
    }
    __syncthreads();
    const int tok = tok_s;

    // ---- 2) stage x = emb[tok] and h_in into LDS ----
    const float* xrow = emb + (size_t)tok * EMB;
    for (int i = tid; i < EMB; i += 256) xs[i] = xrow[i];
    for (int i = tid; i < HID; i += 256) hs[i] = h_in[i];
    __syncthreads();

    // ---- 3) one wave computes the 4 gate dot-products for unit j ----
    const int j = blockIdx.x * 4 + wave;   // NB_GAT*4 == HID exactly
    float gv[4];
    #pragma unroll
    for (int g = 0; g < 4; ++g) {
        const int row = g * HID + j;
        const float* wi = W_ih + (size_t)row * EMB;
        const float* wh = W_hh + (size_t)row * HID;
        float acc = 0.0f;
        #pragma unroll
        for (int k = lane * 4; k < EMB; k += 256) {
            float4 w4 = *(const float4*)(wi + k);
            float4 x4 = *(const float4*)(xs + k);
            acc += w4.x * x4.x + w4.y * x4.y + w4.z * x4.z + w4.w * x4.w;
        }
        #pragma unroll
        for (int k = lane * 4; k < HID; k += 256) {
            float4 w4 = *(const float4*)(wh + k);
            float4 h4 = *(const float4*)(hs + k);
            acc += w4.x * h4.x + w4.y * h4.y + w4.z * h4.z + w4.w * h4.w;
        }
        for (int off = 32; off; off >>= 1) acc += __shfl_down(acc, off);
        gv[g] = acc;   // meaningful on lane 0
    }

    // ---- 4) LSTM cell update (lane 0 of each wave owns unit j) ----
    if (lane == 0) {
        float gi = gv[0] + b_ih[j]           + b_hh[j];
        float gf = gv[1] + b_ih[HID + j]     + b_hh[HID + j];
        float gg = gv[2] + b_ih[2 * HID + j] + b_hh[2 * HID + j];
        float go = gv[3] + b_ih[3 * HID + j] + b_hh[3 * HID + j];
        float iv = 1.0f / (1.0f + expf(-gi));
        float fv = 1.0f / (1.0f + expf(-gf));
        float gvv = tanhf(gg);
        float ov = 1.0f / (1.0f + expf(-go));
        float cn = fv * c[j] + iv * gvv;
        c[j] = cn;
        h_out[j] = ov * tanhf(cn);
    }
}

// One wave per vocab row; writes logits row for this step + per-block argmax.
__global__ __launch_bounds__(256) void k_logits(
    const float* __restrict__ W_out, const float* __restrict__ b_out,
    const float* __restrict__ h, float* __restrict__ out,
    float* __restrict__ bmax, int* __restrict__ bidx, int step)
{
    __shared__ float hs[HID];
    __shared__ float redv[4];
    __shared__ int   redi[4];

    const int tid  = threadIdx.x;
    const int wave = tid >> 6;
    const int lane = tid & 63;

    for (int i = tid; i < HID; i += 256) hs[i] = h[i];
    __syncthreads();

    float* orow = out + (size_t)step * VOCAB;
    float bv = NEG_INF; int bi = 0x7fffffff;

    for (int r = blockIdx.x * 4 + wave; r < VOCAB; r += NB_LOG * 4) {
        const float* w = W_out + (size_t)r * HID;
        float acc = 0.0f;
        #pragma unroll
        for (int k = lane * 4; k < HID; k += 256) {
            float4 w4 = *(const float4*)(w + k);
            float4 h4 = *(const float4*)(hs + k);
            acc += w4.x * h4.x + w4.y * h4.y + w4.z * h4.z + w4.w * h4.w;
        }
        for (int off = 32; off; off >>= 1) acc += __shfl_down(acc, off);
        if (lane == 0) {
            float v = acc + b_out[r];
            orow[r] = v;
            if (v > bv) { bv = v; bi = r; }   // r strictly increasing per wave
        }
    }

    if (lane == 0) { redv[wave] = bv; redi[wave] = bi; }
    __syncthreads();
    if (tid == 0) {
        for (int w = 1; w < 4; ++w)
            if (redv[w] > bv || (redv[w] == bv && redi[w] < bi)) { bv = redv[w]; bi = redi[w]; }
        bmax[blockIdx.x] = bv;
        bidx[blockIdx.x] = bi;
    }
}

extern "C" void kernel_launch(void* const* d_in, const int* in_sizes, int n_in,
                              void* d_out, int out_size, void* d_ws, size_t ws_size,
                              hipStream_t stream) {
    const float* emb   = (const float*)d_in[0];
    const float* W_ih  = (const float*)d_in[1];
    const float* W_hh  = (const float*)d_in[2];
    const float* b_ih  = (const float*)d_in[3];
    const float* b_hh  = (const float*)d_in[4];
    const float* W_out = (const float*)d_in[5];
    const float* b_out = (const float*)d_in[6];
    float* out = (float*)d_out;

    float* ws   = (float*)d_ws;
    float* hA   = ws;                 // step-even input h
    float* hB   = ws + HID;
    float* c    = ws + 2 * HID;
    float* bmax = ws + 3 * HID;
    int*   bidx = (int*)(ws + 3 * HID + NB_LOG);

    k_init<<<(3 * HID + 255) / 256, 256, 0, stream>>>(ws);

    for (int t = 0; t < T; ++t) {
        float* h_in  = (t & 1) ? hB : hA;
        float* h_out = (t & 1) ? hA : hB;
        k_gates<<<NB_GAT, 256, 0, stream>>>(emb, W_ih, W_hh, b_ih, b_hh,
                                            h_in, h_out, c, bmax, bidx, t);
        k_logits<<<NB_LOG, 256, 0, stream>>>(W_out, b_out, h_out, out, bmax, bidx, t);
    }
}